// Round 18
// baseline (100.308 us; speedup 1.0000x reference)
//
#include <hip/hip_runtime.h>
#include <math.h>

#define BATCH 4
#define LQ 2048
#define LK 2048
#define DIM 16
#define HEADS 2
#define DH 8
#define EPS 1e-5f

typedef float fvec4 __attribute__((ext_vector_type(4)));
typedef unsigned int uvec4 __attribute__((ext_vector_type(4)));
typedef unsigned int uvec2 __attribute__((ext_vector_type(2)));
typedef __fp16 hvec2 __attribute__((ext_vector_type(2)));   // matches builtin sigs

__device__ __forceinline__ hvec2 u2h(unsigned u) {
    union { unsigned u; hvec2 h; } c; c.u = u; return c.h;
}
__device__ __forceinline__ unsigned h2u(hvec2 h) {
    union { unsigned u; hvec2 h; } c; c.h = h; return c.u;
}

// ---------------- Kernel A: fused LayerNorm + Linear for q,k,v ------------
// Q: fp32 (B,H,L,DH) pre-scaled. K: fp16 half2 dim-pairs Kh[bh][p][col].
// V: fp16 scalar Vh[bh][d][col]. q-branch also initializes out = xn + bo.
__global__ __launch_bounds__(256) void ln_proj3_kernel(
    const float* __restrict__ xq, const float* __restrict__ xk,
    const float* __restrict__ xv,
    const float* __restrict__ gq, const float* __restrict__ bq_ln,
    const float* __restrict__ gk, const float* __restrict__ bk_ln,
    const float* __restrict__ gv, const float* __restrict__ bv_ln,
    const float* __restrict__ Wq, const float* __restrict__ bq,
    const float* __restrict__ Wk, const float* __restrict__ bk,
    const float* __restrict__ Wv, const float* __restrict__ bv,
    const float* __restrict__ bo,          // out-proj bias (for out init)
    float* __restrict__ outbuf,            // (B,LQ,16): init to q0 + bo
    float* __restrict__ Qb, unsigned* __restrict__ Kh,
    unsigned short* __restrict__ Vh)
{
    const int gid = blockIdx.x * blockDim.x + threadIdx.x;
    const int which = gid >> 13;          // 0=q 1=k 2=v (uniform per block)
    const int r     = gid & 8191;

    const float* x; const float* g; const float* bl;
    const float* W; const float* bb; float scale;
    if (which == 0)      { x = xq; g = gq; bl = bq_ln; W = Wq; bb = bq; scale = 0.35355339059327373f; }
    else if (which == 1) { x = xk; g = gk; bl = bk_ln; W = Wk; bb = bk; scale = 1.0f; }
    else                 { x = xv; g = gv; bl = bv_ln; W = Wv; bb = bv; scale = 1.0f; }

    float xv16[16];
    const float4* xp = (const float4*)(x + (size_t)r * 16);
#pragma unroll
    for (int i = 0; i < 4; ++i) {
        float4 t = xp[i];
        xv16[4*i+0] = t.x; xv16[4*i+1] = t.y; xv16[4*i+2] = t.z; xv16[4*i+3] = t.w;
    }
    float m = 0.f;
#pragma unroll
    for (int i = 0; i < 16; ++i) m += xv16[i];
    m *= (1.f / 16.f);
    float var = 0.f;
#pragma unroll
    for (int i = 0; i < 16; ++i) { float d = xv16[i] - m; var += d * d; }
    var *= (1.f / 16.f);
    float rs = rsqrtf(var + EPS);

    float xn[16];
#pragma unroll
    for (int i = 0; i < 16; ++i) xn[i] = (xv16[i] - m) * rs * g[i] + bl[i];

    if (which == 0) {
        // out init = post-LN query (residual) + out-proj bias
        float4* op = (float4*)(outbuf + (size_t)r * 16);
#pragma unroll
        for (int i = 0; i < 4; ++i) {
            float4 t;
            t.x = xn[4*i+0] + bo[4*i+0]; t.y = xn[4*i+1] + bo[4*i+1];
            t.z = xn[4*i+2] + bo[4*i+2]; t.w = xn[4*i+3] + bo[4*i+3];
            op[i] = t;
        }
    }

    float pr[16];
#pragma unroll
    for (int j = 0; j < 16; ++j) {
        float acc = bb[j];
#pragma unroll
        for (int i = 0; i < 16; ++i) acc += xn[i] * W[j * 16 + i];
        pr[j] = acc * scale;
    }

    const int b = r >> 11;
    const int l = r & 2047;
    if (which == 0) {
#pragma unroll
        for (int j = 0; j < 16; ++j) {
            int h = j >> 3, d = j & 7;
            Qb[((((size_t)b * HEADS + h) * 2048) + l) * DH + d] = pr[j];
        }
    } else if (which == 1) {
#pragma unroll
        for (int h = 0; h < 2; ++h) {
            unsigned* Kpan = Kh + ((size_t)(b * 2 + h)) * 8192;
#pragma unroll
            for (int p = 0; p < 4; ++p) {
                hvec2 hk = __builtin_amdgcn_cvt_pkrtz(pr[h * 8 + 2 * p], pr[h * 8 + 2 * p + 1]);
                Kpan[p * 2048 + l] = h2u(hk);
            }
        }
    } else {
#pragma unroll
        for (int h = 0; h < 2; ++h) {
            unsigned short* Vpan = Vh + ((size_t)(b * 2 + h)) * 16384;
#pragma unroll
            for (int d = 0; d < 8; ++d) {
                union { __fp16 h; unsigned short u; } cv;
                cv.h = (__fp16)pr[h * 8 + d];
                Vpan[d * 2048 + l] = cv.u;
            }
        }
    }
}

// ---- Kernel B: 512 threads / 8 waves; each wave owns HALF a q-row
//      (1024 cols). K+V fp16 panel in 64KB LDS; per-wave prefetch is only
//      8 fvec4 (32 regs) -> VGPR <=128 -> 2 blocks/CU = 16 waves/CU.
//      Loop body has ZERO global loads so the pre-barrier prefetch cannot
//      be sunk (r13/r15 mechanism). Row sum/ctx combined across the two
//      half-row waves via a small LDS exchange + second (lgkm-only) barrier.
__device__ __forceinline__ float wave_sum(float v) {
#pragma unroll
    for (int off = 32; off > 0; off >>= 1) v += __shfl_xor(v, off);
    return v;
}

// (512,2): hipcc arg2 = blocks/CU -> VGPR cap 128 (r3/r6/r15 evidence).
// Tripwire: WRITE_SIZE > 133MB => spill => revert to r15.
__global__ __launch_bounds__(512, 2) void attn_kernel(
    const float* __restrict__ Q,          // (B,H,LQ,DH) pre-scaled
    const unsigned* __restrict__ Kh,      // [bh][p][2048] half2 dim-pairs
    const unsigned* __restrict__ Vh,      // [bh][d][1024] half2 col-pairs (u32 view)
    const float* __restrict__ w,
    const float* __restrict__ mask,
    const float* __restrict__ Wo,         // (16,16)
    float* __restrict__ attn_out,         // (B,H,LQ,LK)
    float* __restrict__ outbuf)           // (B,LQ,16), pre-initialized
{
    __shared__ unsigned Kp[4][2048];            // 32 KB
    __shared__ unsigned Vp[8][1024];            // 32 KB
    __shared__ __align__(16) float psum[8];     // per-wave partial sums
    __shared__ __align__(16) float pcd[8][8];   // per-wave partial ctx

    const int t    = threadIdx.x;
    const int lane = t & 63;
    const int wid  = t >> 6;                    // 0..7
    const int rsub = wid >> 1;                  // 0..3: row within block
    const int half = wid & 1;                   // 0..1: column half
    const int gr   = (blockIdx.x << 2) + rsub;  // global row
    const int bh   = gr >> 11;                  // uniform per block (512|2048)
    const int q    = gr & (LQ - 1);
    const int h    = bh & (HEADS - 1);
    const int b    = bh >> 1;

    const unsigned* Kpan = Kh + (size_t)bh * 8192;
    const unsigned* Vpan = Vh + (size_t)bh * 8192;

    // ---- stage K+V panel (L2-resident source): 8 uvec4 copies/thread ----
    {
        const uvec4* Ksrc = (const uvec4*)Kpan;   // 2048 uvec4
        const uvec4* Vsrc = (const uvec4*)Vpan;   // 2048 uvec4
        uvec4* Kdst = (uvec4*)&Kp[0][0];
        uvec4* Vdst = (uvec4*)&Vp[0][0];
#pragma unroll
        for (int j = 0; j < 4; ++j) {
            Kdst[(j << 9) + t] = Ksrc[(j << 9) + t];
            Vdst[(j << 9) + t] = Vsrc[(j << 9) + t];
        }
    }

    // q -> 4 packed half2 dim-pairs (own row)
    const float* Qrow = Q + (size_t)gr * DH;
    hvec2 qpk[4];
#pragma unroll
    for (int p = 0; p < 4; ++p) qpk[p] = __builtin_amdgcn_cvt_pkrtz(Qrow[2 * p], Qrow[2 * p + 1]);

    const float* wrow = w    + (size_t)gr * LK;
    const float* mrow = mask + (size_t)gr * LK;

    // ---- HALF-ROW prefetch: 8 fvec4 (4KB/wave) pinned by the barrier ----
    fvec4 wb[4], mb[4];
#pragma unroll
    for (int g = 0; g < 4; ++g) {
        const int col = (half << 10) + (g << 8) + (lane << 2);
        wb[g] = __builtin_nontemporal_load((const fvec4*)(wrow + col));
        mb[g] = __builtin_nontemporal_load((const fvec4*)(mrow + col));
    }

    __syncthreads();   // barrier 1: LDS staged + prefetch pinned

    unsigned epk[8];             // e as half2 col-pairs (4 groups x 2)
    float sum = 0.f;
    float cd[8] = {0,0,0,0,0,0,0,0};

#pragma unroll
    for (int i = 0; i < 4; ++i) {
        const fvec4 wv = wb[i], mv = mb[i];
        const int cb = (half << 10) + (i << 8) + (lane << 2);
        uvec4 kk0 = *(const uvec4*)&Kp[0][cb];
        uvec4 kk1 = *(const uvec4*)&Kp[1][cb];
        uvec4 kk2 = *(const uvec4*)&Kp[2][cb];
        uvec4 kk3 = *(const uvec4*)&Kp[3][cb];
        float e[4];
#pragma unroll
        for (int j = 0; j < 4; ++j) {
            // -4 shift: softmax-invariant, keeps e in fp16 range
            float sj = wv[j] + mv[j] - 4.0f;
            sj = __builtin_amdgcn_fdot2(qpk[0], u2h(kk0[j]), sj, false);
            sj = __builtin_amdgcn_fdot2(qpk[1], u2h(kk1[j]), sj, false);
            sj = __builtin_amdgcn_fdot2(qpk[2], u2h(kk2[j]), sj, false);
            sj = __builtin_amdgcn_fdot2(qpk[3], u2h(kk3[j]), sj, false);
            e[j] = __expf(sj);
        }
        sum += (e[0] + e[1]) + (e[2] + e[3]);
        hvec2 e01 = __builtin_amdgcn_cvt_pkrtz(e[0], e[1]);
        hvec2 e23 = __builtin_amdgcn_cvt_pkrtz(e[2], e[3]);
        epk[2 * i]     = h2u(e01);
        epk[2 * i + 1] = h2u(e23);
        const int cp = cb >> 1;
#pragma unroll
        for (int d = 0; d < 8; ++d) {
            uvec2 vv = *(const uvec2*)&Vp[d][cp];
            cd[d] = __builtin_amdgcn_fdot2(e01, u2h(vv.x), cd[d], false);
            cd[d] = __builtin_amdgcn_fdot2(e23, u2h(vv.y), cd[d], false);
        }
    }

    // wave-level reductions; publish partials to LDS
    sum = wave_sum(sum);
#pragma unroll
    for (int d = 0; d < 8; ++d) cd[d] = wave_sum(cd[d]);
    if (lane == 0) {
        psum[wid] = sum;
        fvec4 c0; c0.x = cd[0]; c0.y = cd[1]; c0.z = cd[2]; c0.w = cd[3];
        fvec4 c1; c1.x = cd[4]; c1.y = cd[5]; c1.z = cd[6]; c1.w = cd[7];
        *(fvec4*)&pcd[wid][0] = c0;
        *(fvec4*)&pcd[wid][4] = c1;
    }

    __syncthreads();   // barrier 2: combine the two half-row partials

    const int pair = wid & 6;                   // partner pair base
    const float rsum = psum[pair] + psum[pair | 1];
    const float inv = 1.f / rsum;

    // normalized attn half-row: unpack fp16 e, scale, nontemporal stores
    float* arow = attn_out + (size_t)gr * LK;
#pragma unroll
    for (int g = 0; g < 4; ++g) {
        const int col = (half << 10) + (g << 8) + (lane << 2);
        hvec2 e01 = u2h(epk[2 * g]), e23 = u2h(epk[2 * g + 1]);
        fvec4 o;
        o.x = (float)e01.x * inv; o.y = (float)e01.y * inv;
        o.z = (float)e23.x * inv; o.w = (float)e23.y * inv;
        __builtin_nontemporal_store(o, (fvec4*)(arow + col));
    }

    // fused out-projection: half==0 wave combines both halves' ctx and
    // adds this head's contribution (lanes 0-15, 2-way atomic contention).
    if (half == 0 && lane < 16) {
        const float* wo = Wo + lane * 16 + h * 8;
        float acc = 0.f;
#pragma unroll
        for (int p = 0; p < 8; ++p)
            acc += (pcd[wid][p] + pcd[wid + 1][p]) * wo[p];
        atomicAdd(&outbuf[((size_t)(b * LQ + q)) * 16 + lane], acc * inv);
    }
}

extern "C" void kernel_launch(void* const* d_in, const int* in_sizes, int n_in,
                              void* d_out, int out_size, void* d_ws, size_t ws_size,
                              hipStream_t stream) {
    const float* query = (const float*)d_in[0];
    const float* key_  = (const float*)d_in[1];
    const float* value = (const float*)d_in[2];
    const float* w     = (const float*)d_in[3];
    const float* mask  = (const float*)d_in[4];
    const float* ln_qg = (const float*)d_in[5];
    const float* ln_qb = (const float*)d_in[6];
    const float* ln_kg = (const float*)d_in[7];
    const float* ln_kb = (const float*)d_in[8];
    const float* ln_vg = (const float*)d_in[9];
    const float* ln_vb = (const float*)d_in[10];
    const float* Wq = (const float*)d_in[11];
    const float* bq = (const float*)d_in[12];
    const float* Wk = (const float*)d_in[13];
    const float* bk = (const float*)d_in[14];
    const float* Wv = (const float*)d_in[15];
    const float* bv = (const float*)d_in[16];
    const float* Wo = (const float*)d_in[17];
    const float* bo = (const float*)d_in[18];

    float* out  = (float*)d_out;                       // (B,LQ,16) first
    float* attn = out + (size_t)BATCH * LQ * DIM;      // then (B,H,LQ,LK)

    const size_t NE = (size_t)BATCH * LQ * DIM;        // 131072
    float* ws  = (float*)d_ws;
    float* Qb  = ws;                          // 131072 f
    unsigned* Kh = (unsigned*)(Qb + NE);      // 65536 u32  (8 panels x 8192)
    unsigned short* Vh16 = (unsigned short*)(Kh + 65536);  // 131072 u16
    unsigned* Vh = (unsigned*)Vh16;           // u32 view: [bh][d][1024]

    // 2 launches total. ln_proj3 also initializes out = q0 + bo.
    ln_proj3_kernel<<<(3 * 8192) / 256, 256, 0, stream>>>(
        query, key_, value,
        ln_qg, ln_qb, ln_kg, ln_kb, ln_vg, ln_vb,
        Wq, bq, Wk, bk, Wv, bv,
        bo, out, Qb, Kh, Vh16);

    // 4096 blocks x 8 waves; wave = half-row; K+V in LDS; 2 barriers.
    attn_kernel<<<BATCH * HEADS * LQ / 4, 512, 0, stream>>>(
        Qb, Kh, Vh, w, mask, Wo, attn, out);
}

// Round 19
// 95.797 us; speedup vs baseline: 1.0471x; 1.0471x over previous
//
#include <hip/hip_runtime.h>
#include <math.h>

#define BATCH 4
#define LQ 2048
#define LK 2048
#define DIM 16
#define HEADS 2
#define DH 8
#define EPS 1e-5f

typedef float fvec4 __attribute__((ext_vector_type(4)));
typedef unsigned int uvec4 __attribute__((ext_vector_type(4)));
typedef unsigned int uvec2 __attribute__((ext_vector_type(2)));
typedef __fp16 hvec2 __attribute__((ext_vector_type(2)));   // matches builtin sigs

__device__ __forceinline__ hvec2 u2h(unsigned u) {
    union { unsigned u; hvec2 h; } c; c.u = u; return c.h;
}
__device__ __forceinline__ unsigned h2u(hvec2 h) {
    union { unsigned u; hvec2 h; } c; c.h = h; return c.u;
}

// ---------------- Kernel A: fused LayerNorm + Linear for q,k,v ------------
// Q: fp32 (B,H,L,DH) pre-scaled. K: fp16 half2 dim-pairs Kh[bh][p][col].
// V: fp16 scalar Vh[bh][d][col]. q-branch also initializes out = xn + bo.
__global__ __launch_bounds__(256) void ln_proj3_kernel(
    const float* __restrict__ xq, const float* __restrict__ xk,
    const float* __restrict__ xv,
    const float* __restrict__ gq, const float* __restrict__ bq_ln,
    const float* __restrict__ gk, const float* __restrict__ bk_ln,
    const float* __restrict__ gv, const float* __restrict__ bv_ln,
    const float* __restrict__ Wq, const float* __restrict__ bq,
    const float* __restrict__ Wk, const float* __restrict__ bk,
    const float* __restrict__ Wv, const float* __restrict__ bv,
    const float* __restrict__ bo,          // out-proj bias (for out init)
    float* __restrict__ outbuf,            // (B,LQ,16): init to q0 + bo
    float* __restrict__ Qb, unsigned* __restrict__ Kh,
    unsigned short* __restrict__ Vh)
{
    const int gid = blockIdx.x * blockDim.x + threadIdx.x;
    const int which = gid >> 13;          // 0=q 1=k 2=v (uniform per block)
    const int r     = gid & 8191;

    const float* x; const float* g; const float* bl;
    const float* W; const float* bb; float scale;
    if (which == 0)      { x = xq; g = gq; bl = bq_ln; W = Wq; bb = bq; scale = 0.35355339059327373f; }
    else if (which == 1) { x = xk; g = gk; bl = bk_ln; W = Wk; bb = bk; scale = 1.0f; }
    else                 { x = xv; g = gv; bl = bv_ln; W = Wv; bb = bv; scale = 1.0f; }

    float xv16[16];
    const float4* xp = (const float4*)(x + (size_t)r * 16);
#pragma unroll
    for (int i = 0; i < 4; ++i) {
        float4 t = xp[i];
        xv16[4*i+0] = t.x; xv16[4*i+1] = t.y; xv16[4*i+2] = t.z; xv16[4*i+3] = t.w;
    }
    float m = 0.f;
#pragma unroll
    for (int i = 0; i < 16; ++i) m += xv16[i];
    m *= (1.f / 16.f);
    float var = 0.f;
#pragma unroll
    for (int i = 0; i < 16; ++i) { float d = xv16[i] - m; var += d * d; }
    var *= (1.f / 16.f);
    float rs = rsqrtf(var + EPS);

    float xn[16];
#pragma unroll
    for (int i = 0; i < 16; ++i) xn[i] = (xv16[i] - m) * rs * g[i] + bl[i];

    if (which == 0) {
        // out init = post-LN query (residual) + out-proj bias
        float4* op = (float4*)(outbuf + (size_t)r * 16);
#pragma unroll
        for (int i = 0; i < 4; ++i) {
            float4 t;
            t.x = xn[4*i+0] + bo[4*i+0]; t.y = xn[4*i+1] + bo[4*i+1];
            t.z = xn[4*i+2] + bo[4*i+2]; t.w = xn[4*i+3] + bo[4*i+3];
            op[i] = t;
        }
    }

    float pr[16];
#pragma unroll
    for (int j = 0; j < 16; ++j) {
        float acc = bb[j];
#pragma unroll
        for (int i = 0; i < 16; ++i) acc += xn[i] * W[j * 16 + i];
        pr[j] = acc * scale;
    }

    const int b = r >> 11;
    const int l = r & 2047;
    if (which == 0) {
#pragma unroll
        for (int j = 0; j < 16; ++j) {
            int h = j >> 3, d = j & 7;
            Qb[((((size_t)b * HEADS + h) * 2048) + l) * DH + d] = pr[j];
        }
    } else if (which == 1) {
#pragma unroll
        for (int h = 0; h < 2; ++h) {
            unsigned* Kpan = Kh + ((size_t)(b * 2 + h)) * 8192;
#pragma unroll
            for (int p = 0; p < 4; ++p) {
                hvec2 hk = __builtin_amdgcn_cvt_pkrtz(pr[h * 8 + 2 * p], pr[h * 8 + 2 * p + 1]);
                Kpan[p * 2048 + l] = h2u(hk);
            }
        }
    } else {
#pragma unroll
        for (int h = 0; h < 2; ++h) {
            unsigned short* Vpan = Vh + ((size_t)(b * 2 + h)) * 16384;
#pragma unroll
            for (int d = 0; d < 8; ++d) {
                union { __fp16 h; unsigned short u; } cv;
                cv.h = (__fp16)pr[h * 8 + d];
                Vpan[d * 2048 + l] = cv.u;
            }
        }
    }
}

// ---- Kernel B: r15 per-wave structure, 512-thread blocks (8 waves, 8 rows).
//      K+V fp16 panel in 64KB LDS; EACH wave prefetches its FULL w+mask row
//      (16 fvec4, 8KB) BEFORE the single barrier (un-sinkable). 8 waves x
//      16KB = 128KB in flight per block; 2 blocks/CU = 16 waves/CU. ----
__device__ __forceinline__ float wave_sum(float v) {
#pragma unroll
    for (int off = 32; off > 0; off >>= 1) v += __shfl_xor(v, off);
    return v;
}

// (512,2): 2 blocks x 8 waves = 4 waves/SIMD -> VGPR cap 128. Kernel needs
// ~108. Tripwires: VGPR=128 + WRITE>140MB => spilled; VGPR ~68 => prefetch
// sunk. Either way r15 is the fallback.
__global__ __launch_bounds__(512, 2) void attn_kernel(
    const float* __restrict__ Q,          // (B,H,LQ,DH) pre-scaled
    const unsigned* __restrict__ Kh,      // [bh][p][2048] half2 dim-pairs
    const unsigned* __restrict__ Vh,      // [bh][d][1024] half2 col-pairs (u32 view)
    const float* __restrict__ w,
    const float* __restrict__ mask,
    const float* __restrict__ Wo,         // (16,16)
    float* __restrict__ attn_out,         // (B,H,LQ,LK)
    float* __restrict__ outbuf)           // (B,LQ,16), pre-initialized
{
    __shared__ unsigned Kp[4][2048];   // 32 KB
    __shared__ unsigned Vp[8][1024];   // 32 KB

    const int t    = threadIdx.x;
    const int lane = t & 63;
    const int wid  = t >> 6;                      // 0..7, one q-row per wave
    const int gr   = (blockIdx.x << 3) + wid;     // global row
    const int bh   = gr >> 11;                    // uniform per block (8|2048)
    const int q    = gr & (LQ - 1);
    const int rowid= gr;
    const int h    = bh & (HEADS - 1);
    const int b    = bh >> 1;

    const unsigned* Kpan = Kh + (size_t)bh * 8192;
    const unsigned* Vpan = Vh + (size_t)bh * 8192;

    // ---- stage K+V panel (L2-resident source): 8 uvec4 copies/thread ----
    {
        const uvec4* Ksrc = (const uvec4*)Kpan;   // 2048 uvec4
        const uvec4* Vsrc = (const uvec4*)Vpan;   // 2048 uvec4
        uvec4* Kdst = (uvec4*)&Kp[0][0];
        uvec4* Vdst = (uvec4*)&Vp[0][0];
#pragma unroll
        for (int j = 0; j < 4; ++j) {
            Kdst[(j << 9) + t] = Ksrc[(j << 9) + t];
            Vdst[(j << 9) + t] = Vsrc[(j << 9) + t];
        }
    }

    // q -> 4 packed half2 dim-pairs
    const float* Qrow = Q + (size_t)rowid * DH;
    hvec2 qpk[4];
#pragma unroll
    for (int p = 0; p < 4; ++p) qpk[p] = __builtin_amdgcn_cvt_pkrtz(Qrow[2 * p], Qrow[2 * p + 1]);

    const float* wrow = w    + (size_t)rowid * LK;
    const float* mrow = mask + (size_t)rowid * LK;

    // ---- FULL-ROW prefetch: 16 fvec4 (8KB) in flight, overlaps staging;
    //      issued before the barrier so the compiler cannot sink them. ----
    fvec4 wb[8], mb[8];
#pragma unroll
    for (int g = 0; g < 8; ++g) {
        const int col = (g << 8) + (lane << 2);
        wb[g] = __builtin_nontemporal_load((const fvec4*)(wrow + col));
        mb[g] = __builtin_nontemporal_load((const fvec4*)(mrow + col));
    }

    __syncthreads();   // the ONLY barrier

    unsigned epk[16];            // e as half2 col-pairs
    float sum = 0.f;
    float cd[8] = {0,0,0,0,0,0,0,0};

#pragma unroll
    for (int i = 0; i < 8; ++i) {
        const fvec4 wv = wb[i], mv = mb[i];
        const int cb = (i << 8) + (lane << 2);
        uvec4 kk0 = *(const uvec4*)&Kp[0][cb];
        uvec4 kk1 = *(const uvec4*)&Kp[1][cb];
        uvec4 kk2 = *(const uvec4*)&Kp[2][cb];
        uvec4 kk3 = *(const uvec4*)&Kp[3][cb];
        float e[4];
#pragma unroll
        for (int j = 0; j < 4; ++j) {
            // -4 shift: softmax-invariant, keeps e in fp16 range
            float sj = wv[j] + mv[j] - 4.0f;
            sj = __builtin_amdgcn_fdot2(qpk[0], u2h(kk0[j]), sj, false);
            sj = __builtin_amdgcn_fdot2(qpk[1], u2h(kk1[j]), sj, false);
            sj = __builtin_amdgcn_fdot2(qpk[2], u2h(kk2[j]), sj, false);
            sj = __builtin_amdgcn_fdot2(qpk[3], u2h(kk3[j]), sj, false);
            e[j] = __expf(sj);
        }
        sum += (e[0] + e[1]) + (e[2] + e[3]);
        hvec2 e01 = __builtin_amdgcn_cvt_pkrtz(e[0], e[1]);
        hvec2 e23 = __builtin_amdgcn_cvt_pkrtz(e[2], e[3]);
        epk[2 * i]     = h2u(e01);
        epk[2 * i + 1] = h2u(e23);
        const int cp = cb >> 1;
#pragma unroll
        for (int d = 0; d < 8; ++d) {
            uvec2 vv = *(const uvec2*)&Vp[d][cp];
            cd[d] = __builtin_amdgcn_fdot2(e01, u2h(vv.x), cd[d], false);
            cd[d] = __builtin_amdgcn_fdot2(e23, u2h(vv.y), cd[d], false);
        }
    }

    sum = wave_sum(sum);
    const float inv = 1.f / sum;

    // normalized attn row: unpack fp16 e, scale, nontemporal fvec4 stores
    float* arow = attn_out + (size_t)rowid * LK;
#pragma unroll
    for (int g = 0; g < 8; ++g) {
        const int col = (g << 8) + (lane << 2);
        hvec2 e01 = u2h(epk[2 * g]), e23 = u2h(epk[2 * g + 1]);
        fvec4 o;
        o.x = (float)e01.x * inv; o.y = (float)e01.y * inv;
        o.z = (float)e23.x * inv; o.w = (float)e23.y * inv;
        __builtin_nontemporal_store(o, (fvec4*)(arow + col));
    }

    // fused out-projection: lanes 0-15 add this head's contribution
#pragma unroll
    for (int d = 0; d < 8; ++d) cd[d] = wave_sum(cd[d]) * inv;
    if (lane < 16) {
        const float* wo = Wo + lane * 16 + h * 8;
        float acc = 0.f;
#pragma unroll
        for (int p = 0; p < 8; ++p) acc += cd[p] * wo[p];
        atomicAdd(&outbuf[((size_t)(b * LQ + q)) * 16 + lane], acc);
    }
}

extern "C" void kernel_launch(void* const* d_in, const int* in_sizes, int n_in,
                              void* d_out, int out_size, void* d_ws, size_t ws_size,
                              hipStream_t stream) {
    const float* query = (const float*)d_in[0];
    const float* key_  = (const float*)d_in[1];
    const float* value = (const float*)d_in[2];
    const float* w     = (const float*)d_in[3];
    const float* mask  = (const float*)d_in[4];
    const float* ln_qg = (const float*)d_in[5];
    const float* ln_qb = (const float*)d_in[6];
    const float* ln_kg = (const float*)d_in[7];
    const float* ln_kb = (const float*)d_in[8];
    const float* ln_vg = (const float*)d_in[9];
    const float* ln_vb = (const float*)d_in[10];
    const float* Wq = (const float*)d_in[11];
    const float* bq = (const float*)d_in[12];
    const float* Wk = (const float*)d_in[13];
    const float* bk = (const float*)d_in[14];
    const float* Wv = (const float*)d_in[15];
    const float* bv = (const float*)d_in[16];
    const float* Wo = (const float*)d_in[17];
    const float* bo = (const float*)d_in[18];

    float* out  = (float*)d_out;                       // (B,LQ,16) first
    float* attn = out + (size_t)BATCH * LQ * DIM;      // then (B,H,LQ,LK)

    const size_t NE = (size_t)BATCH * LQ * DIM;        // 131072
    float* ws  = (float*)d_ws;
    float* Qb  = ws;                          // 131072 f
    unsigned* Kh = (unsigned*)(Qb + NE);      // 65536 u32  (8 panels x 8192)
    unsigned short* Vh16 = (unsigned short*)(Kh + 65536);  // 131072 u16
    unsigned* Vh = (unsigned*)Vh16;           // u32 view: [bh][d][1024]

    // 2 launches total. ln_proj3 also initializes out = q0 + bo.
    ln_proj3_kernel<<<(3 * 8192) / 256, 256, 0, stream>>>(
        query, key_, value,
        ln_qg, ln_qb, ln_kg, ln_kb, ln_vg, ln_vb,
        Wq, bq, Wk, bk, Wv, bv,
        bo, out, Qb, Kh, Vh16);

    // 2048 blocks x 8 waves x 1 row; K+V in LDS; one barrier; fused out-proj.
    attn_kernel<<<BATCH * HEADS * LQ / 8, 512, 0, stream>>>(
        Qb, Kh, Vh, w, mask, Wo, attn, out);
}

// Round 20
// 80.797 us; speedup vs baseline: 1.2415x; 1.1856x over previous
//
#include <hip/hip_runtime.h>
#include <math.h>

#define BATCH 4
#define LQ 2048
#define LK 2048
#define DIM 16
#define HEADS 2
#define DH 8
#define EPS 1e-5f

typedef float fvec4 __attribute__((ext_vector_type(4)));
typedef unsigned int uvec4 __attribute__((ext_vector_type(4)));
typedef unsigned int uvec2 __attribute__((ext_vector_type(2)));
typedef __fp16 hvec2 __attribute__((ext_vector_type(2)));   // matches builtin sigs

__device__ __forceinline__ hvec2 u2h(unsigned u) {
    union { unsigned u; hvec2 h; } c; c.u = u; return c.h;
}
__device__ __forceinline__ unsigned h2u(hvec2 h) {
    union { unsigned u; hvec2 h; } c; c.h = h; return c.u;
}

// ---------------- Kernel A: fused LayerNorm + Linear for q,k,v ------------
// Q: fp32 (B,H,L,DH) pre-scaled. K: fp16 half2 dim-pairs Kh[bh][p][col].
// V: fp16 scalar Vh[bh][d][col]. q-branch also initializes out = xn + bo.
__global__ __launch_bounds__(256) void ln_proj3_kernel(
    const float* __restrict__ xq, const float* __restrict__ xk,
    const float* __restrict__ xv,
    const float* __restrict__ gq, const float* __restrict__ bq_ln,
    const float* __restrict__ gk, const float* __restrict__ bk_ln,
    const float* __restrict__ gv, const float* __restrict__ bv_ln,
    const float* __restrict__ Wq, const float* __restrict__ bq,
    const float* __restrict__ Wk, const float* __restrict__ bk,
    const float* __restrict__ Wv, const float* __restrict__ bv,
    const float* __restrict__ bo,          // out-proj bias (for out init)
    float* __restrict__ outbuf,            // (B,LQ,16): init to q0 + bo
    float* __restrict__ Qb, unsigned* __restrict__ Kh,
    unsigned short* __restrict__ Vh)
{
    const int gid = blockIdx.x * blockDim.x + threadIdx.x;
    const int which = gid >> 13;          // 0=q 1=k 2=v (uniform per block)
    const int r     = gid & 8191;

    const float* x; const float* g; const float* bl;
    const float* W; const float* bb; float scale;
    if (which == 0)      { x = xq; g = gq; bl = bq_ln; W = Wq; bb = bq; scale = 0.35355339059327373f; }
    else if (which == 1) { x = xk; g = gk; bl = bk_ln; W = Wk; bb = bk; scale = 1.0f; }
    else                 { x = xv; g = gv; bl = bv_ln; W = Wv; bb = bv; scale = 1.0f; }

    float xv16[16];
    const float4* xp = (const float4*)(x + (size_t)r * 16);
#pragma unroll
    for (int i = 0; i < 4; ++i) {
        float4 t = xp[i];
        xv16[4*i+0] = t.x; xv16[4*i+1] = t.y; xv16[4*i+2] = t.z; xv16[4*i+3] = t.w;
    }
    float m = 0.f;
#pragma unroll
    for (int i = 0; i < 16; ++i) m += xv16[i];
    m *= (1.f / 16.f);
    float var = 0.f;
#pragma unroll
    for (int i = 0; i < 16; ++i) { float d = xv16[i] - m; var += d * d; }
    var *= (1.f / 16.f);
    float rs = rsqrtf(var + EPS);

    float xn[16];
#pragma unroll
    for (int i = 0; i < 16; ++i) xn[i] = (xv16[i] - m) * rs * g[i] + bl[i];

    if (which == 0) {
        // out init = post-LN query (residual) + out-proj bias
        float4* op = (float4*)(outbuf + (size_t)r * 16);
#pragma unroll
        for (int i = 0; i < 4; ++i) {
            float4 t;
            t.x = xn[4*i+0] + bo[4*i+0]; t.y = xn[4*i+1] + bo[4*i+1];
            t.z = xn[4*i+2] + bo[4*i+2]; t.w = xn[4*i+3] + bo[4*i+3];
            op[i] = t;
        }
    }

    float pr[16];
#pragma unroll
    for (int j = 0; j < 16; ++j) {
        float acc = bb[j];
#pragma unroll
        for (int i = 0; i < 16; ++i) acc += xn[i] * W[j * 16 + i];
        pr[j] = acc * scale;
    }

    const int b = r >> 11;
    const int l = r & 2047;
    if (which == 0) {
#pragma unroll
        for (int j = 0; j < 16; ++j) {
            int h = j >> 3, d = j & 7;
            Qb[((((size_t)b * HEADS + h) * 2048) + l) * DH + d] = pr[j];
        }
    } else if (which == 1) {
#pragma unroll
        for (int h = 0; h < 2; ++h) {
            unsigned* Kpan = Kh + ((size_t)(b * 2 + h)) * 8192;
#pragma unroll
            for (int p = 0; p < 4; ++p) {
                hvec2 hk = __builtin_amdgcn_cvt_pkrtz(pr[h * 8 + 2 * p], pr[h * 8 + 2 * p + 1]);
                Kpan[p * 2048 + l] = h2u(hk);
            }
        }
    } else {
#pragma unroll
        for (int h = 0; h < 2; ++h) {
            unsigned short* Vpan = Vh + ((size_t)(b * 2 + h)) * 16384;
#pragma unroll
            for (int d = 0; d < 8; ++d) {
                union { __fp16 h; unsigned short u; } cv;
                cv.h = (__fp16)pr[h * 8 + d];
                Vpan[d * 2048 + l] = cv.u;
            }
        }
    }
}

// ---- Kernel B (r15, the proven optimum): 256 threads / 4 waves / 1 row per
//      wave. fp16 K+V panel in 64KB LDS. FULL w+mask row (16 fvec4, 8KB)
//      prefetched BEFORE the single barrier -> cannot be sunk. Loop body is
//      VMEM-free (K/V from LDS). Epilogue fuses out-projection (atomicAdd).
//      Every structural departure from this shape regressed (r16-r19). ----
__device__ __forceinline__ float wave_sum(float v) {
#pragma unroll
    for (int off = 32; off > 0; off >>= 1) v += __shfl_xor(v, off);
    return v;
}

// (256,2): VGPR cap 256 -- room for the 64 buffer regs without spill.
__global__ __launch_bounds__(256, 2) void attn_kernel(
    const float* __restrict__ Q,          // (B,H,LQ,DH) pre-scaled
    const unsigned* __restrict__ Kh,      // [bh][p][2048] half2 dim-pairs
    const unsigned* __restrict__ Vh,      // [bh][d][1024] half2 col-pairs (u32 view)
    const float* __restrict__ w,
    const float* __restrict__ mask,
    const float* __restrict__ Wo,         // (16,16)
    float* __restrict__ attn_out,         // (B,H,LQ,LK)
    float* __restrict__ outbuf)           // (B,LQ,16), pre-initialized
{
    __shared__ unsigned Kp[4][2048];   // 32 KB
    __shared__ unsigned Vp[8][1024];   // 32 KB

    const int t    = threadIdx.x;
    const int lane = t & 63;
    const int wid  = t >> 6;                      // 0..3, one q-row per wave
    const int gr   = (blockIdx.x << 2) + wid;     // global row
    const int bh   = gr >> 11;
    const int q    = gr & (LQ - 1);
    const int rowid= gr;
    const int h    = bh & (HEADS - 1);
    const int b    = bh >> 1;

    const unsigned* Kpan = Kh + (size_t)bh * 8192;
    const unsigned* Vpan = Vh + (size_t)bh * 8192;

    // ---- stage K+V panel (L2-resident source): 16 uvec4 copies/thread ----
    {
        const uvec4* Ksrc = (const uvec4*)Kpan;   // 2048 uvec4
        const uvec4* Vsrc = (const uvec4*)Vpan;   // 2048 uvec4
        uvec4* Kdst = (uvec4*)&Kp[0][0];
        uvec4* Vdst = (uvec4*)&Vp[0][0];
#pragma unroll
        for (int j = 0; j < 8; ++j) {
            Kdst[(j << 8) + t] = Ksrc[(j << 8) + t];
            Vdst[(j << 8) + t] = Vsrc[(j << 8) + t];
        }
    }

    // q -> 4 packed half2 dim-pairs
    const float* Qrow = Q + (size_t)rowid * DH;
    hvec2 qpk[4];
#pragma unroll
    for (int p = 0; p < 4; ++p) qpk[p] = __builtin_amdgcn_cvt_pkrtz(Qrow[2 * p], Qrow[2 * p + 1]);

    const float* wrow = w    + (size_t)rowid * LK;
    const float* mrow = mask + (size_t)rowid * LK;

    // ---- FULL-ROW prefetch: 16 fvec4 (8KB) in flight, overlaps staging;
    //      issued before the barrier so the compiler cannot sink them. ----
    fvec4 wb[8], mb[8];
#pragma unroll
    for (int g = 0; g < 8; ++g) {
        const int col = (g << 8) + (lane << 2);
        wb[g] = __builtin_nontemporal_load((const fvec4*)(wrow + col));
        mb[g] = __builtin_nontemporal_load((const fvec4*)(mrow + col));
    }

    __syncthreads();   // the ONLY barrier

    unsigned epk[16];            // e as half2 col-pairs
    float sum = 0.f;
    float cd[8] = {0,0,0,0,0,0,0,0};

#pragma unroll
    for (int i = 0; i < 8; ++i) {
        const fvec4 wv = wb[i], mv = mb[i];
        const int cb = (i << 8) + (lane << 2);
        uvec4 kk0 = *(const uvec4*)&Kp[0][cb];
        uvec4 kk1 = *(const uvec4*)&Kp[1][cb];
        uvec4 kk2 = *(const uvec4*)&Kp[2][cb];
        uvec4 kk3 = *(const uvec4*)&Kp[3][cb];
        float e[4];
#pragma unroll
        for (int j = 0; j < 4; ++j) {
            // -4 shift: softmax-invariant, keeps e in fp16 range
            float sj = wv[j] + mv[j] - 4.0f;
            sj = __builtin_amdgcn_fdot2(qpk[0], u2h(kk0[j]), sj, false);
            sj = __builtin_amdgcn_fdot2(qpk[1], u2h(kk1[j]), sj, false);
            sj = __builtin_amdgcn_fdot2(qpk[2], u2h(kk2[j]), sj, false);
            sj = __builtin_amdgcn_fdot2(qpk[3], u2h(kk3[j]), sj, false);
            e[j] = __expf(sj);
        }
        sum += (e[0] + e[1]) + (e[2] + e[3]);
        hvec2 e01 = __builtin_amdgcn_cvt_pkrtz(e[0], e[1]);
        hvec2 e23 = __builtin_amdgcn_cvt_pkrtz(e[2], e[3]);
        epk[2 * i]     = h2u(e01);
        epk[2 * i + 1] = h2u(e23);
        const int cp = cb >> 1;
#pragma unroll
        for (int d = 0; d < 8; ++d) {
            uvec2 vv = *(const uvec2*)&Vp[d][cp];
            cd[d] = __builtin_amdgcn_fdot2(e01, u2h(vv.x), cd[d], false);
            cd[d] = __builtin_amdgcn_fdot2(e23, u2h(vv.y), cd[d], false);
        }
    }

    sum = wave_sum(sum);
    const float inv = 1.f / sum;

    // normalized attn row: unpack fp16 e, scale, nontemporal fvec4 stores
    float* arow = attn_out + (size_t)rowid * LK;
#pragma unroll
    for (int g = 0; g < 8; ++g) {
        const int col = (g << 8) + (lane << 2);
        hvec2 e01 = u2h(epk[2 * g]), e23 = u2h(epk[2 * g + 1]);
        fvec4 o;
        o.x = (float)e01.x * inv; o.y = (float)e01.y * inv;
        o.z = (float)e23.x * inv; o.w = (float)e23.y * inv;
        __builtin_nontemporal_store(o, (fvec4*)(arow + col));
    }

    // fused out-projection: lanes 0-15 add this head's contribution
#pragma unroll
    for (int d = 0; d < 8; ++d) cd[d] = wave_sum(cd[d]) * inv;
    if (lane < 16) {
        const float* wo = Wo + lane * 16 + h * 8;
        float acc = 0.f;
#pragma unroll
        for (int p = 0; p < 8; ++p) acc += cd[p] * wo[p];
        atomicAdd(&outbuf[((size_t)(b * LQ + q)) * 16 + lane], acc);
    }
}

extern "C" void kernel_launch(void* const* d_in, const int* in_sizes, int n_in,
                              void* d_out, int out_size, void* d_ws, size_t ws_size,
                              hipStream_t stream) {
    const float* query = (const float*)d_in[0];
    const float* key_  = (const float*)d_in[1];
    const float* value = (const float*)d_in[2];
    const float* w     = (const float*)d_in[3];
    const float* mask  = (const float*)d_in[4];
    const float* ln_qg = (const float*)d_in[5];
    const float* ln_qb = (const float*)d_in[6];
    const float* ln_kg = (const float*)d_in[7];
    const float* ln_kb = (const float*)d_in[8];
    const float* ln_vg = (const float*)d_in[9];
    const float* ln_vb = (const float*)d_in[10];
    const float* Wq = (const float*)d_in[11];
    const float* bq = (const float*)d_in[12];
    const float* Wk = (const float*)d_in[13];
    const float* bk = (const float*)d_in[14];
    const float* Wv = (const float*)d_in[15];
    const float* bv = (const float*)d_in[16];
    const float* Wo = (const float*)d_in[17];
    const float* bo = (const float*)d_in[18];

    float* out  = (float*)d_out;                       // (B,LQ,16) first
    float* attn = out + (size_t)BATCH * LQ * DIM;      // then (B,H,LQ,LK)

    const size_t NE = (size_t)BATCH * LQ * DIM;        // 131072
    float* ws  = (float*)d_ws;
    float* Qb  = ws;                          // 131072 f
    unsigned* Kh = (unsigned*)(Qb + NE);      // 65536 u32  (8 panels x 8192)
    unsigned short* Vh16 = (unsigned short*)(Kh + 65536);  // 131072 u16
    unsigned* Vh = (unsigned*)Vh16;           // u32 view: [bh][d][1024]

    // 2 launches total. ln_proj3 also initializes out = q0 + bo.
    ln_proj3_kernel<<<(3 * 8192) / 256, 256, 0, stream>>>(
        query, key_, value,
        ln_qg, ln_qb, ln_kg, ln_kb, ln_vg, ln_vb,
        Wq, bq, Wk, bk, Wv, bv,
        bo, out, Qb, Kh, Vh16);

    // 4096 blocks x 4 waves; K+V in LDS; one barrier; fused out-proj.
    attn_kernel<<<BATCH * HEADS * LQ / 4, 256, 0, stream>>>(
        Qb, Kh, Vh, w, mask, Wo, attn, out);
}